// Round 3
// baseline (541.396 us; speedup 1.0000x reference)
//
#include <hip/hip_runtime.h>
#include <hip/hip_bf16.h>

#define PW 64
#define NV 512
#define HW 256
#define COV 16
#define BATCH 2048
#define XROW (PW * NV + COV)   // 32784

typedef short s16x8 __attribute__((ext_vector_type(8)));
typedef float f32x4 __attribute__((ext_vector_type(4)));

__device__ __forceinline__ unsigned short f2bf(float f) {
    union { float f; unsigned int u; } v;
    v.f = f;
    unsigned int u = v.u;
    unsigned int r = (u + 0x7fffu + ((u >> 16) & 1u)) >> 16;   // RNE
    return (unsigned short)r;
}

// packed f32x2 -> bf16x2 (v_cvt_pk_bf16_f32 on gfx950, RNE)
__device__ __forceinline__ unsigned int pack2(float a, float b) {
    __hip_bfloat162 h = __float22bfloat162_rn(float2{a, b});
    union { __hip_bfloat162 h; unsigned int u; } c;
    c.h = h;
    return c.u;
}

// ---------------------------------------------------------------------------
// Transpose + fp32->bf16 convert for BOTH weight tensors in one dispatch.
// W1: 64 x (512 x 256) -> 64 x (256 x 512);  W2: 64 x (256 x 256) -> same T.
// Tile decode: first 8192 blocks are W1 tiles (8 c-tiles x 16 r-tiles x 64 p),
// next 4096 are W2 tiles (8 x 8 x 64).
// ---------------------------------------------------------------------------
__global__ __launch_bounds__(256)
void transpose_all(const float* __restrict__ W1, const float* __restrict__ W2,
                   unsigned short* __restrict__ W1T, unsigned short* __restrict__ W2T) {
    __shared__ float tile[32][33];
    const float* in;
    unsigned short* out;
    int R, C, c0, r0, p;
    int bx = blockIdx.x;
    if (bx < 8192) {               // W1 tile
        R = NV; C = HW;
        c0 = (bx & 7) * 32;
        r0 = ((bx >> 3) & 15) * 32;
        p  = bx >> 7;
        in = W1; out = W1T;
    } else {                       // W2 tile
        bx -= 8192;
        R = HW; C = HW;
        c0 = (bx & 7) * 32;
        r0 = ((bx >> 3) & 7) * 32;
        p  = bx >> 6;
        in = W2; out = W2T;
    }
    const float* ip = in + (size_t)p * R * C;
    unsigned short* op = out + (size_t)p * R * C;
    const int tx = threadIdx.x & 31;
    const int ty = threadIdx.x >> 5;   // 0..7
    #pragma unroll
    for (int j = 0; j < 32; j += 8)
        tile[ty + j][tx] = ip[(size_t)(r0 + ty + j) * C + c0 + tx];
    __syncthreads();
    #pragma unroll
    for (int j = 0; j < 32; j += 8)
        op[(size_t)(c0 + ty + j) * R + r0 + tx] = f2bf(tile[tx][ty + j]);
}

// ---------------------------------------------------------------------------
// Grouped GEMM, 128x256 tile (full N), fused LeakyReLU.
//   A: (2048 x K) fp32 (CONV_A, pack-converted during staging) or bf16
//   BT: (256 x K) bf16 N-major
//   FUSE=false: Hout[p] = lrelu(A@B) as bf16 (2048 x 256)
//   FUSE=true : pvec[p][row] = lrelu( sum_n lrelu(A@B)[row][n] * W3[p][n] )
// 4 waves: 2(M) x 2(N), each wave 64x128 via 4x8 grid of 16x16x32 bf16 MFMA.
// ---------------------------------------------------------------------------
template<int K, bool CONV_A, bool FUSE>
__global__ __launch_bounds__(256)
void gemm_fused(const void* __restrict__ Abase, const unsigned short* __restrict__ BT,
                unsigned short* __restrict__ Hout, const float* __restrict__ W3,
                float* __restrict__ pvec, int lda, long aPs) {
    __shared__ __align__(16) unsigned short As[128][72];   // +8 pad
    __shared__ __align__(16) unsigned short Bs[256][72];
    __shared__ float red[2][128];

    const int p   = blockIdx.z;
    const int bm0 = blockIdx.x * 128;
    const int t    = threadIdx.x;
    const int lane = t & 63;
    const int wave = t >> 6;
    const int wm  = (wave & 1) * 64;
    const int wni = wave >> 1;          // 0 or 1
    const int wn  = wni * 128;
    const int l15  = lane & 15;
    const int quad = lane >> 4;

    f32x4 acc[4][8] = {};

    const unsigned short* Bp = BT + (size_t)p * HW * K;

    for (int k0 = 0; k0 < K; k0 += 64) {
        if (CONV_A) {
            const float* Ap = (const float*)Abase + (size_t)p * aPs;
            #pragma unroll
            for (int i = 0; i < 8; ++i) {
                int idx = t + i * 256;           // 0..2047
                int row = idx >> 4;              // 16 float4 per 64-wide row
                int c4  = (idx & 15) * 4;
                float4 v = *(const float4*)(Ap + (size_t)(bm0 + row) * lda + k0 + c4);
                uint2 u;
                u.x = pack2(v.x, v.y);
                u.y = pack2(v.z, v.w);
                *(uint2*)&As[row][c4] = u;
            }
        } else {
            const unsigned short* Ap = (const unsigned short*)Abase + (size_t)p * aPs;
            #pragma unroll
            for (int i = 0; i < 4; ++i) {
                int idx = t + i * 256;           // 0..1023
                int row = idx >> 3;              // 8 x 16B chunks per 64-wide row
                int c8  = (idx & 7) * 8;
                *(s16x8*)&As[row][c8] = *(const s16x8*)(Ap + (size_t)(bm0 + row) * lda + k0 + c8);
            }
        }
        #pragma unroll
        for (int i = 0; i < 8; ++i) {
            int idx = t + i * 256;               // 0..2047
            int row = idx >> 3;                  // 0..255
            int c8  = (idx & 7) * 8;
            *(s16x8*)&Bs[row][c8] = *(const s16x8*)(Bp + (size_t)row * K + k0 + c8);
        }
        __syncthreads();

        #pragma unroll
        for (int kk = 0; kk < 64; kk += 32) {
            s16x8 af[4], bfr[8];
            #pragma unroll
            for (int mi = 0; mi < 4; ++mi)
                af[mi] = *(const s16x8*)&As[wm + mi * 16 + l15][kk + quad * 8];
            #pragma unroll
            for (int ni = 0; ni < 8; ++ni)
                bfr[ni] = *(const s16x8*)&Bs[wn + ni * 16 + l15][kk + quad * 8];
            #pragma unroll
            for (int mi = 0; mi < 4; ++mi)
                #pragma unroll
                for (int ni = 0; ni < 8; ++ni)
                    acc[mi][ni] = __builtin_amdgcn_mfma_f32_16x16x32_bf16(
                        af[mi], bfr[ni], acc[mi][ni], 0, 0, 0);
        }
        __syncthreads();
    }

    if (!FUSE) {
        // lrelu + convert + store (C/D layout: col=lane&15, row=quad*4+reg)
        unsigned short* Cp = Hout + (size_t)p * BATCH * HW;
        #pragma unroll
        for (int mi = 0; mi < 4; ++mi) {
            #pragma unroll
            for (int ni = 0; ni < 8; ++ni) {
                int col = wn + ni * 16 + l15;
                #pragma unroll
                for (int r = 0; r < 4; ++r) {
                    int row = bm0 + wm + mi * 16 + quad * 4 + r;
                    float v = acc[mi][ni][r];
                    v = v >= 0.f ? v : 0.2f * v;
                    Cp[(size_t)row * HW + col] = f2bf(v);
                }
            }
        }
    } else {
        // fused dot with W3 over all 256 columns (H2 stays in registers, f32)
        float w3v[8];
        #pragma unroll
        for (int ni = 0; ni < 8; ++ni)
            w3v[ni] = W3[(size_t)p * HW + wn + ni * 16 + l15];
        float part[4][4];
        #pragma unroll
        for (int mi = 0; mi < 4; ++mi) {
            #pragma unroll
            for (int r = 0; r < 4; ++r) {
                float s = 0.f;
                #pragma unroll
                for (int ni = 0; ni < 8; ++ni) {
                    float v = acc[mi][ni][r];
                    v = v >= 0.f ? v : 0.2f * v;
                    s += v * w3v[ni];
                }
                part[mi][r] = s;
            }
        }
        #pragma unroll
        for (int off = 1; off < 16; off <<= 1)
            #pragma unroll
            for (int mi = 0; mi < 4; ++mi)
                #pragma unroll
                for (int r = 0; r < 4; ++r)
                    part[mi][r] += __shfl_xor(part[mi][r], off);
        if (l15 == 0) {
            #pragma unroll
            for (int mi = 0; mi < 4; ++mi)
                #pragma unroll
                for (int r = 0; r < 4; ++r)
                    red[wni][wm + mi * 16 + quad * 4 + r] = part[mi][r];
        }
        __syncthreads();
        if (t < 128) {
            float s = red[0][t] + red[1][t];
            s = s >= 0.f ? s : 0.2f * s;
            pvec[(size_t)p * BATCH + bm0 + t] = s;
        }
    }
}

// ---------------------------------------------------------------------------
// All batch statistics in ONE dispatch (single block, 16 waves):
//   per-pathway sum/sumsq -> mean, invstd, and closed-form Frobenius norm
//   ||pn||^2 = sum_p B * (gamma^2 * var/(var+eps) + beta^2)
// stat layout: [0..63]=mean, [64..127]=invstd, [128]=1/norm
// ---------------------------------------------------------------------------
__global__ __launch_bounds__(1024)
void stats_all(const float* __restrict__ pvec, const float* __restrict__ gamma,
               const float* __restrict__ beta, float* __restrict__ stat) {
    __shared__ float sm[64], sq[64];
    const int wave = threadIdx.x >> 6;
    const int lane = threadIdx.x & 63;
    #pragma unroll
    for (int pp = 0; pp < 4; ++pp) {
        const int p = wave * 4 + pp;
        float s = 0.f, q = 0.f;
        for (int i = lane; i < BATCH; i += 64) {
            float v = pvec[(size_t)p * BATCH + i];
            s += v; q += v * v;
        }
        #pragma unroll
        for (int off = 32; off; off >>= 1) {
            s += __shfl_down(s, off);
            q += __shfl_down(q, off);
        }
        if (lane == 0) { sm[p] = s; sq[p] = q; }
    }
    __syncthreads();
    if (threadIdx.x < 64) {
        const int p = threadIdx.x;
        float mean = sm[p] * (1.f / BATCH);
        float var  = sq[p] * (1.f / BATCH) - mean * mean;
        float invstd = rsqrtf(var + 1e-5f);
        stat[p]      = mean;
        stat[64 + p] = invstd;
        float g = gamma[p], bt = beta[p];
        float contrib = (float)BATCH * (g * g * var / (var + 1e-5f) + bt * bt);
        #pragma unroll
        for (int off = 32; off; off >>= 1) contrib += __shfl_down(contrib, off);
        if (p == 0) stat[128] = rsqrtf(contrib);
    }
}

// ---------------------------------------------------------------------------
// Final: batchnorm-apply, /norm, concat covariates, linear, sigmoid.
// ---------------------------------------------------------------------------
__global__ __launch_bounds__(256)
void final_k(const float* __restrict__ pvec, const float* __restrict__ stat,
             const float* __restrict__ gamma, const float* __restrict__ beta,
             const float* __restrict__ x, const float* __restrict__ fc_w,
             const float* __restrict__ fc_b, float* __restrict__ out) {
    const int b = blockIdx.x * 256 + threadIdx.x;
    const float rn = stat[128];
    float acc = fc_b[0];
    #pragma unroll
    for (int p = 0; p < PW; ++p) {
        float pn = (pvec[(size_t)p * BATCH + b] - stat[p]) * stat[64 + p] * gamma[p] + beta[p];
        acc += pn * rn * fc_w[p];
    }
    #pragma unroll
    for (int c = 0; c < COV; ++c)
        acc += x[(size_t)b * XROW + PW * NV + c] * fc_w[PW + c];
    out[b] = 1.f / (1.f + __expf(-acc));
}

// ---------------------------------------------------------------------------
extern "C" void kernel_launch(void* const* d_in, const int* in_sizes, int n_in,
                              void* d_out, int out_size, void* d_ws, size_t ws_size,
                              hipStream_t stream) {
    const float* x     = (const float*)d_in[0];
    const float* W1    = (const float*)d_in[1];
    const float* W2    = (const float*)d_in[2];
    const float* W3    = (const float*)d_in[3];
    const float* gamma = (const float*)d_in[4];
    const float* beta  = (const float*)d_in[5];
    const float* fc_w  = (const float*)d_in[6];
    const float* fc_b  = (const float*)d_in[7];
    float* out = (float*)d_out;

    char* ws = (char*)d_ws;
    size_t off = 0;
    unsigned short* W1T = (unsigned short*)(ws + off); off += (size_t)PW * NV * HW * 2;      // 16.78 MB
    unsigned short* W2T = (unsigned short*)(ws + off); off += (size_t)PW * HW * HW * 2;      //  8.39 MB
    unsigned short* H1  = (unsigned short*)(ws + off); off += (size_t)PW * BATCH * HW * 2;   // 67.1 MB
    float* pvec = (float*)(ws + off); off += (size_t)PW * BATCH * 4;                          // 0.5 MB
    float* stat = (float*)(ws + off); off += 256 * 4;

    // 1) both weight transposes in one dispatch
    transpose_all<<<dim3(8192 + 4096), 256, 0, stream>>>(W1, W2, W1T, W2T);

    // 2) H1 = lrelu(x_p @ W1_p)   (A fp32, pack-converted in staging; x read ONCE)
    gemm_fused<NV, true, false><<<dim3(BATCH / 128, 1, PW), 256, 0, stream>>>(
        (const void*)x, W1T, H1, nullptr, nullptr, XROW, (long)NV);

    // 3) pvec = lrelu( lrelu(H1_p @ W2_p) . W3_p )   (H2 never materialized)
    gemm_fused<HW, false, true><<<dim3(BATCH / 128, 1, PW), 256, 0, stream>>>(
        (const void*)H1, W2T, nullptr, W3, pvec, HW, (long)BATCH * HW);

    // 4) all stats in one dispatch
    stats_all<<<1, 1024, 0, stream>>>(pvec, gamma, beta, stat);

    // 5) final head
    final_k<<<BATCH / 256, 256, 0, stream>>>(pvec, stat, gamma, beta, x, fc_w, fc_b, out);
}

// Round 4
// 461.055 us; speedup vs baseline: 1.1743x; 1.1743x over previous
//
#include <hip/hip_runtime.h>
#include <hip/hip_bf16.h>

#define PW 64
#define NV 512
#define HW 256
#define COV 16
#define BATCH 2048
#define XROW (PW * NV + COV)   // 32784

typedef short s16x8 __attribute__((ext_vector_type(8)));
typedef float f32x4 __attribute__((ext_vector_type(4)));

__device__ __forceinline__ unsigned short f2bf(float f) {
    union { float f; unsigned int u; } v;
    v.f = f;
    unsigned int u = v.u;
    unsigned int r = (u + 0x7fffu + ((u >> 16) & 1u)) >> 16;   // RNE
    return (unsigned short)r;
}

// packed f32x2 -> bf16x2 (v_cvt_pk_bf16_f32 on gfx950, RNE)
__device__ __forceinline__ unsigned int pack2(float a, float b) {
    __hip_bfloat162 h = __float22bfloat162_rn(float2{a, b});
    union { __hip_bfloat162 h; unsigned int u; } c;
    c.h = h;
    return c.u;
}

__device__ __forceinline__ float lrelu(float v) { return v >= 0.f ? v : 0.2f * v; }

// ---------------------------------------------------------------------------
// Transpose + fp32->bf16 convert for BOTH weight tensors in one dispatch.
// W1: 64 x (512 x 256) -> N-major 64 x (256 x 512);  W2: 64 x (256 x 256) -> T.
// ---------------------------------------------------------------------------
__global__ __launch_bounds__(256)
void transpose_all(const float* __restrict__ W1, const float* __restrict__ W2,
                   unsigned short* __restrict__ W1T, unsigned short* __restrict__ W2T) {
    __shared__ float tile[32][33];
    const float* in;
    unsigned short* out;
    int R, C, c0, r0, p;
    int bx = blockIdx.x;
    if (bx < 8192) {               // W1 tile: 8 c-tiles x 16 r-tiles x 64 p
        R = NV; C = HW;
        c0 = (bx & 7) * 32;
        r0 = ((bx >> 3) & 15) * 32;
        p  = bx >> 7;
        in = W1; out = W1T;
    } else {                       // W2 tile: 8 x 8 x 64
        bx -= 8192;
        R = HW; C = HW;
        c0 = (bx & 7) * 32;
        r0 = ((bx >> 3) & 7) * 32;
        p  = bx >> 6;
        in = W2; out = W2T;
    }
    const float* ip = in + (size_t)p * R * C;
    unsigned short* op = out + (size_t)p * R * C;
    const int tx = threadIdx.x & 31;
    const int ty = threadIdx.x >> 5;   // 0..7
    #pragma unroll
    for (int j = 0; j < 32; j += 8)
        tile[ty + j][tx] = ip[(size_t)(r0 + ty + j) * C + c0 + tx];
    __syncthreads();
    #pragma unroll
    for (int j = 0; j < 32; j += 8)
        op[(size_t)(c0 + ty + j) * R + r0 + tx] = f2bf(tile[tx][ty + j]);
}

// ---------------------------------------------------------------------------
// FULLY-FUSED pathway kernel: per 64-row tile of one pathway,
//   H1 = lrelu(x_p @ W1_p)        (H1 tile lives in LDS, never hits HBM)
//   H2 = lrelu(H1 @ W2_p)         (in registers)
//   pvec[p][row] = lrelu(H2 . W3_p)
// 4 waves; each wave computes ALL 64 rows x its 64-col slice.
// 16x16x32 bf16 MFMA; BK=64.  LDS = 9.2 + 36.9 + 33.8 + 1 = ~81 KB -> 2 blk/CU.
// ---------------------------------------------------------------------------
__global__ __launch_bounds__(256, 2)
void pathway_fused(const float* __restrict__ x, const unsigned short* __restrict__ W1T,
                   const unsigned short* __restrict__ W2T, const float* __restrict__ W3,
                   float* __restrict__ pvec) {
    __shared__ __align__(16) unsigned short As[64][72];     // x tile (bf16)
    __shared__ __align__(16) unsigned short Bs[256][72];    // weight k-slice
    __shared__ __align__(16) unsigned short H1t[64][264];   // full 64x256 H1 tile
    __shared__ float red[4][64];

    const int bm0 = blockIdx.x * 64;
    const int p   = blockIdx.y;
    const int t    = threadIdx.x;
    const int lane = t & 63;
    const int wave = t >> 6;
    const int wn   = wave * 64;         // this wave's 64-col slice
    const int l15  = lane & 15;
    const int quad = lane >> 4;

    const float* Ap          = x   + (size_t)p * NV;
    const unsigned short* B1 = W1T + (size_t)p * HW * NV;
    const unsigned short* B2 = W2T + (size_t)p * HW * HW;

    // ---------------- stage A: H1 tile = lrelu(x @ W1) ----------------
    {
        f32x4 acc[4][4] = {};
        for (int k0 = 0; k0 < NV; k0 += 64) {
            #pragma unroll
            for (int i = 0; i < 4; ++i) {            // As: 64x64 fp32->bf16
                int idx = t + i * 256;               // 0..1023
                int row = idx >> 4;
                int c4  = (idx & 15) * 4;
                float4 v = *(const float4*)(Ap + (size_t)(bm0 + row) * XROW + k0 + c4);
                uint2 u;
                u.x = pack2(v.x, v.y);
                u.y = pack2(v.z, v.w);
                *(uint2*)&As[row][c4] = u;
            }
            #pragma unroll
            for (int i = 0; i < 8; ++i) {            // Bs: 256 x 64 of W1T
                int idx = t + i * 256;               // 0..2047
                int row = idx >> 3;
                int c8  = (idx & 7) * 8;
                *(s16x8*)&Bs[row][c8] = *(const s16x8*)(B1 + (size_t)row * NV + k0 + c8);
            }
            __syncthreads();
            #pragma unroll
            for (int kk = 0; kk < 64; kk += 32) {
                s16x8 af[4], bfr[4];
                #pragma unroll
                for (int mi = 0; mi < 4; ++mi)
                    af[mi] = *(const s16x8*)&As[mi * 16 + l15][kk + quad * 8];
                #pragma unroll
                for (int ni = 0; ni < 4; ++ni)
                    bfr[ni] = *(const s16x8*)&Bs[wn + ni * 16 + l15][kk + quad * 8];
                #pragma unroll
                for (int mi = 0; mi < 4; ++mi)
                    #pragma unroll
                    for (int ni = 0; ni < 4; ++ni)
                        acc[mi][ni] = __builtin_amdgcn_mfma_f32_16x16x32_bf16(
                            af[mi], bfr[ni], acc[mi][ni], 0, 0, 0);
            }
            __syncthreads();
        }
        // write lrelu(acc) into H1t (C/D layout: col=lane&15, row=quad*4+reg)
        #pragma unroll
        for (int mi = 0; mi < 4; ++mi)
            #pragma unroll
            for (int ni = 0; ni < 4; ++ni)
                #pragma unroll
                for (int r = 0; r < 4; ++r)
                    H1t[mi * 16 + quad * 4 + r][wn + ni * 16 + l15] =
                        f2bf(lrelu(acc[mi][ni][r]));
    }
    __syncthreads();

    // ---------------- stage B: H2 = lrelu(H1 @ W2), fused dot W3 ----------------
    f32x4 acc2[4][4] = {};
    for (int k0 = 0; k0 < HW; k0 += 64) {
        #pragma unroll
        for (int i = 0; i < 8; ++i) {                // Bs: 256 x 64 of W2T
            int idx = t + i * 256;
            int row = idx >> 3;
            int c8  = (idx & 7) * 8;
            *(s16x8*)&Bs[row][c8] = *(const s16x8*)(B2 + (size_t)row * HW + k0 + c8);
        }
        __syncthreads();
        #pragma unroll
        for (int kk = 0; kk < 64; kk += 32) {
            s16x8 af[4], bfr[4];
            #pragma unroll
            for (int mi = 0; mi < 4; ++mi)
                af[mi] = *(const s16x8*)&H1t[mi * 16 + l15][k0 + kk + quad * 8];
            #pragma unroll
            for (int ni = 0; ni < 4; ++ni)
                bfr[ni] = *(const s16x8*)&Bs[wn + ni * 16 + l15][kk + quad * 8];
            #pragma unroll
            for (int mi = 0; mi < 4; ++mi)
                #pragma unroll
                for (int ni = 0; ni < 4; ++ni)
                    acc2[mi][ni] = __builtin_amdgcn_mfma_f32_16x16x32_bf16(
                        af[mi], bfr[ni], acc2[mi][ni], 0, 0, 0);
        }
        __syncthreads();
    }

    // dot with W3 over this wave's 64 cols (H2 stays f32 in registers)
    float w3v[4];
    #pragma unroll
    for (int ni = 0; ni < 4; ++ni)
        w3v[ni] = W3[(size_t)p * HW + wn + ni * 16 + l15];
    float part[4][4];
    #pragma unroll
    for (int mi = 0; mi < 4; ++mi) {
        #pragma unroll
        for (int r = 0; r < 4; ++r) {
            float s = 0.f;
            #pragma unroll
            for (int ni = 0; ni < 4; ++ni)
                s += lrelu(acc2[mi][ni][r]) * w3v[ni];
            part[mi][r] = s;
        }
    }
    #pragma unroll
    for (int off = 1; off < 16; off <<= 1)
        #pragma unroll
        for (int mi = 0; mi < 4; ++mi)
            #pragma unroll
            for (int r = 0; r < 4; ++r)
                part[mi][r] += __shfl_xor(part[mi][r], off);
    if (l15 == 0)
        #pragma unroll
        for (int mi = 0; mi < 4; ++mi)
            #pragma unroll
            for (int r = 0; r < 4; ++r)
                red[wave][mi * 16 + quad * 4 + r] = part[mi][r];
    __syncthreads();
    if (t < 64) {
        float s = red[0][t] + red[1][t] + red[2][t] + red[3][t];
        pvec[(size_t)p * BATCH + bm0 + t] = lrelu(s);
    }
}

// ---------------------------------------------------------------------------
// Per-pathway batch stats: mean, invstd, var.  64 blocks, one per pathway.
// stat layout: [0..63]=mean, [64..127]=invstd, [128..191]=var
// ---------------------------------------------------------------------------
__global__ __launch_bounds__(256)
void stats_k(const float* __restrict__ pvec, float* __restrict__ stat) {
    const int p = blockIdx.x;
    float s = 0.f, q = 0.f;
    for (int i = threadIdx.x; i < BATCH; i += 256) {
        float v = pvec[(size_t)p * BATCH + i];
        s += v; q += v * v;
    }
    #pragma unroll
    for (int off = 32; off; off >>= 1) {
        s += __shfl_down(s, off);
        q += __shfl_down(q, off);
    }
    __shared__ float ls[4], lq[4];
    const int wave = threadIdx.x >> 6, lane = threadIdx.x & 63;
    if (lane == 0) { ls[wave] = s; lq[wave] = q; }
    __syncthreads();
    if (threadIdx.x == 0) {
        float S = ls[0] + ls[1] + ls[2] + ls[3];
        float Q = lq[0] + lq[1] + lq[2] + lq[3];
        float mean = S * (1.f / BATCH);
        float var  = Q * (1.f / BATCH) - mean * mean;
        stat[p]       = mean;
        stat[64 + p]  = rsqrtf(var + 1e-5f);
        stat[128 + p] = var;
    }
}

// ---------------------------------------------------------------------------
// Final: closed-form global norm ||pn||^2 = sum_p B*(g^2*var/(var+eps)+beta^2),
// then batchnorm-apply, /norm, covariates, linear, sigmoid.
// ---------------------------------------------------------------------------
__global__ __launch_bounds__(256)
void final_k(const float* __restrict__ pvec, const float* __restrict__ stat,
             const float* __restrict__ gamma, const float* __restrict__ beta,
             const float* __restrict__ x, const float* __restrict__ fc_w,
             const float* __restrict__ fc_b, float* __restrict__ out) {
    const int b = blockIdx.x * 256 + threadIdx.x;
    float nsq = 0.f;
    #pragma unroll
    for (int p = 0; p < PW; ++p) {
        float g = gamma[p], bt = beta[p], var = stat[128 + p], inv = stat[64 + p];
        nsq += (float)BATCH * (g * g * var * inv * inv + bt * bt);
    }
    const float rn = rsqrtf(nsq);
    float acc = fc_b[0];
    #pragma unroll
    for (int p = 0; p < PW; ++p) {
        float pn = (pvec[(size_t)p * BATCH + b] - stat[p]) * stat[64 + p] * gamma[p] + beta[p];
        acc += pn * rn * fc_w[p];
    }
    #pragma unroll
    for (int c = 0; c < COV; ++c)
        acc += x[(size_t)b * XROW + PW * NV + c] * fc_w[PW + c];
    out[b] = 1.f / (1.f + __expf(-acc));
}

// ---------------------------------------------------------------------------
extern "C" void kernel_launch(void* const* d_in, const int* in_sizes, int n_in,
                              void* d_out, int out_size, void* d_ws, size_t ws_size,
                              hipStream_t stream) {
    const float* x     = (const float*)d_in[0];
    const float* W1    = (const float*)d_in[1];
    const float* W2    = (const float*)d_in[2];
    const float* W3    = (const float*)d_in[3];
    const float* gamma = (const float*)d_in[4];
    const float* beta  = (const float*)d_in[5];
    const float* fc_w  = (const float*)d_in[6];
    const float* fc_b  = (const float*)d_in[7];
    float* out = (float*)d_out;

    char* ws = (char*)d_ws;
    size_t off = 0;
    unsigned short* W1T = (unsigned short*)(ws + off); off += (size_t)PW * NV * HW * 2;  // 16.78 MB
    unsigned short* W2T = (unsigned short*)(ws + off); off += (size_t)PW * HW * HW * 2;  //  8.39 MB
    float* pvec = (float*)(ws + off); off += (size_t)PW * BATCH * 4;                      //  0.5 MB
    float* stat = (float*)(ws + off); off += 256 * 4;

    // 1) both weight transposes in one dispatch
    transpose_all<<<dim3(8192 + 4096), 256, 0, stream>>>(W1, W2, W1T, W2T);

    // 2) fully-fused pathway MLP: x -> pvec  (H1 in LDS, H2 in registers)
    pathway_fused<<<dim3(BATCH / 64, PW), 256, 0, stream>>>(x, W1T, W2T, W3, pvec);

    // 3) per-pathway stats (64 blocks)
    stats_k<<<PW, 256, 0, stream>>>(pvec, stat);

    // 4) final head (norm computed closed-form in-kernel)
    final_k<<<BATCH / 256, 256, 0, stream>>>(pvec, stat, gamma, beta, x, fc_w, fc_b, out);
}